// Round 1
// 1343.033 us; speedup vs baseline: 1.0669x; 1.0669x over previous
//
#include <hip/hip_runtime.h>
#include <hip/hip_bf16.h>
#include <cstddef>
#include <cstdint>

#define HC 32      // H*C
#define NHEADS 2
#define CH 16
#define CAP 96     // fixed per-node edge bucket; P(deg>=96)~1e-18 for Poisson(33)

#define KK    1433   // Fin
#define KFULL 1408   // 44 full BK=32 tiles
#define WTP   1440   // padded Wt row stride (bf16), 16B-aligned rows

typedef __bf16 bf16x8 __attribute__((ext_vector_type(8)));
typedef float  f32x4  __attribute__((ext_vector_type(4)));
typedef float  f32x4u __attribute__((ext_vector_type(4), aligned(4)));

#define BM 128

// ---------------- W prep: fp32 [K][32]x2 -> bf16 transposed [64][1440] ------
// Wt[n][k] = (n<32 ? Wl[k][n] : Wr[k][n-32]), zero-padded for k>=1433.
__global__ __launch_bounds__(256) void wprep(
    const float* __restrict__ Wl, const float* __restrict__ Wr,
    __bf16* __restrict__ Wt)
{
    int idx = blockIdx.x * 256 + threadIdx.x;
    if (idx >= 64 * WTP) return;
    int n = idx / WTP;
    int k = idx - n * WTP;
    float v = 0.f;
    if (k < KK) v = (n < HC) ? Wl[(size_t)k * HC + n]
                             : Wr[(size_t)k * HC + (n - HC)];
    Wt[idx] = (__bf16)v;
}

// ---------------- Layer-1 GEMM via bf16 MFMA, zero LDS / zero barriers ------
// Each wave owns 32 rows x 64 cols (32 XL | 32 XR). A-fragments loaded
// directly from global (8 consecutive fp32 per lane, cvt to bf16 in-reg);
// B-fragments loaded directly from the L2-resident bf16 Wt. No staging, no
// __syncthreads -> waves fully independent, loads pipeline across K.
__global__ __launch_bounds__(256) void gemm_dual_mfma(
    const float* __restrict__ A, int N,
    const __bf16* __restrict__ Wt,
    float* __restrict__ XL, float* __restrict__ XR)
{
    const int tid  = threadIdx.x;
    const int lane = tid & 63;
    const int w    = tid >> 6;
    const int row0 = blockIdx.x * BM;
    const int frag_m = lane & 15;
    const int frag_k = lane >> 4;        // 0..3

    f32x4 acc[2][4];
    #pragma unroll
    for (int i = 0; i < 2; ++i)
        #pragma unroll
        for (int j = 0; j < 4; ++j) acc[i][j] = (f32x4){0.f, 0.f, 0.f, 0.f};

    // A rows for this lane's fragments (clamped; invalid rows store-guarded)
    int r0 = row0 + w * 32 + frag_m;
    int r1 = r0 + 16;
    int cr0 = (r0 < N) ? r0 : N - 1;
    int cr1 = (r1 < N) ? r1 : N - 1;
    const float* __restrict__ a0 = A + (size_t)cr0 * KK + frag_k * 8;
    const float* __restrict__ a1 = A + (size_t)cr1 * KK + frag_k * 8;
    const __bf16* __restrict__ wb = Wt + (size_t)frag_m * WTP + frag_k * 8;

    #pragma unroll 4
    for (int k0 = 0; k0 < KFULL; k0 += 32) {
        f32x4u u0 = *(const f32x4u*)(a0 + k0);
        f32x4u u1 = *(const f32x4u*)(a0 + k0 + 4);
        f32x4u v0 = *(const f32x4u*)(a1 + k0);
        f32x4u v1 = *(const f32x4u*)(a1 + k0 + 4);
        bf16x8 bfv[4];
        #pragma unroll
        for (int nt = 0; nt < 4; ++nt)
            bfv[nt] = *(const bf16x8*)(wb + (size_t)(nt * 16) * WTP + k0);
        bf16x8 af0, af1;
        #pragma unroll
        for (int j = 0; j < 4; ++j) {
            af0[j]     = (__bf16)u0[j];
            af0[j + 4] = (__bf16)u1[j];
            af1[j]     = (__bf16)v0[j];
            af1[j + 4] = (__bf16)v1[j];
        }
        #pragma unroll
        for (int nt = 0; nt < 4; ++nt) {
            acc[0][nt] = __builtin_amdgcn_mfma_f32_16x16x32_bf16(
                af0, bfv[nt], acc[0][nt], 0, 0, 0);
            acc[1][nt] = __builtin_amdgcn_mfma_f32_16x16x32_bf16(
                af1, bfv[nt], acc[1][nt], 0, 0, 0);
        }
    }

    // ---- K tail (k = 1408..1432): A guarded per element; Wt zero-padded ----
    {
        bf16x8 af0, af1, bfv[4];
        #pragma unroll
        for (int j = 0; j < 8; ++j) {
            int k = KFULL + frag_k * 8 + j;
            float x0 = (k < KK) ? a0[KFULL + j] : 0.f;
            float x1 = (k < KK) ? a1[KFULL + j] : 0.f;
            af0[j] = (__bf16)x0;
            af1[j] = (__bf16)x1;
        }
        #pragma unroll
        for (int nt = 0; nt < 4; ++nt)
            bfv[nt] = *(const bf16x8*)(wb + (size_t)(nt * 16) * WTP + KFULL);
        #pragma unroll
        for (int nt = 0; nt < 4; ++nt) {
            acc[0][nt] = __builtin_amdgcn_mfma_f32_16x16x32_bf16(
                af0, bfv[nt], acc[0][nt], 0, 0, 0);
            acc[1][nt] = __builtin_amdgcn_mfma_f32_16x16x32_bf16(
                af1, bfv[nt], acc[1][nt], 0, 0, 0);
        }
    }

    // ---- epilogue (identical layout to verified LDS version) ----
    const int cl = lane & 15;
    const int rq = (lane >> 4) * 4;
    #pragma unroll
    for (int mt = 0; mt < 2; ++mt) {
        #pragma unroll
        for (int nt = 0; nt < 4; ++nt) {
            int col = nt * 16 + cl;
            float* dst = (col < HC) ? XL : XR;
            int c = (col < HC) ? col : (col - HC);
            #pragma unroll
            for (int r = 0; r < 4; ++r) {
                int grow = row0 + w * 32 + mt * 16 + rq + r;
                if (grow < N) dst[(size_t)grow * HC + c] = acc[mt][nt][r];
            }
        }
    }
}

// ---------------- fp32 GEMM (layer 2, K=32; in-place safe A==XR) ------------
__global__ __launch_bounds__(256) void gemm_dual(
    const float* __restrict__ A, int N, int K,
    const float* __restrict__ Wl, const float* __restrict__ Wr,
    float* __restrict__ XL, float* __restrict__ XR)
{
    __shared__ __align__(16) float As[64][33];
    __shared__ __align__(16) float Ws[32][68];
    const int tid = threadIdx.x;
    const int tx = tid & 15;
    const int ty = tid >> 4;
    const int row0 = blockIdx.x * 64;

    float acc[4][4];
    #pragma unroll
    for (int i = 0; i < 4; ++i)
        #pragma unroll
        for (int j = 0; j < 4; ++j) acc[i][j] = 0.f;

    for (int k0 = 0; k0 < K; k0 += 32) {
        #pragma unroll
        for (int i = 0; i < 8; ++i) {
            int idx = tid + i * 256;
            int r = idx >> 5;
            int kk = idx & 31;
            int gr = row0 + r, gk = k0 + kk;
            As[r][kk] = (gr < N && gk < K) ? A[(size_t)gr * K + gk] : 0.f;
        }
        #pragma unroll
        for (int i = 0; i < 8; ++i) {
            int idx = tid + i * 256;
            int kk = idx >> 6;
            int c = idx & 63;
            int gk = k0 + kk;
            float v = 0.f;
            if (gk < K) v = (c < HC) ? Wl[(size_t)gk * HC + c]
                                     : Wr[(size_t)gk * HC + (c - HC)];
            Ws[kk][c] = v;
        }
        __syncthreads();
        #pragma unroll
        for (int kk = 0; kk < 32; ++kk) {
            const float4 bv = *(const float4*)(&Ws[kk][tx * 4]);
            float av[4];
            #pragma unroll
            for (int i = 0; i < 4; ++i) av[i] = As[ty * 4 + i][kk];
            #pragma unroll
            for (int i = 0; i < 4; ++i) {
                acc[i][0] = fmaf(av[i], bv.x, acc[i][0]);
                acc[i][1] = fmaf(av[i], bv.y, acc[i][1]);
                acc[i][2] = fmaf(av[i], bv.z, acc[i][2]);
                acc[i][3] = fmaf(av[i], bv.w, acc[i][3]);
            }
        }
        __syncthreads();
    }
    #pragma unroll
    for (int i = 0; i < 4; ++i) {
        int gr = row0 + ty * 4 + i;
        if (gr < N) {
            float4 v = make_float4(acc[i][0], acc[i][1], acc[i][2], acc[i][3]);
            int c0 = tx * 4;
            if (c0 < HC) *(float4*)&XL[(size_t)gr * HC + c0] = v;
            else         *(float4*)&XR[(size_t)gr * HC + (c0 - HC)] = v;
        }
    }
}

// ---------------- CSR build: single scatter into fixed-cap buckets ----------
__global__ __launch_bounds__(256) void scatter_fixed(
    const int* __restrict__ src, const int* __restrict__ dst,
    int E, int Etot, int* __restrict__ cnt, int* __restrict__ csr_src)
{
    int e = blockIdx.x * blockDim.x + threadIdx.x;
    if (e >= Etot) return;
    int si, di;
    if (e < E) { si = src[e]; di = dst[e]; }
    else       { si = e - E;  di = si; }
    int pos = atomicAdd(&cnt[di], 1);
    if (pos < CAP) csr_src[(size_t)di * CAP + pos] = si;
}

// ---------------- Gather: per-node softmax-aggregate + bias + ELU -----------
// One wave per dst node; 2 edge slots x 4-deep ILP = 8 edges in flight.
__global__ __launch_bounds__(256) void gather_pass(
    const float* __restrict__ xl, float* __restrict__ xr,
    const float* __restrict__ att, const int* __restrict__ cnt,
    const int* __restrict__ csr_src, const float* __restrict__ bias, int N)
{
    int d = (blockIdx.x * blockDim.x + threadIdx.x) >> 6;
    if (d >= N) return;
    const int lane = threadIdx.x & 63;
    const int c = lane & 31;
    const int eslot = lane >> 5;

    const float xrc  = xr[(size_t)d * HC + c];
    const float attc = att[c];
    const float bc   = bias[c];
    int deg = cnt[d]; if (deg > CAP) deg = CAP;
    const int* __restrict__ row = csr_src + (size_t)d * CAP;

    float accv = 0.f, den = 0.f;
    int p = eslot;
    for (; p + 6 < deg; p += 8) {
        int s0 = row[p], s1 = row[p + 2], s2 = row[p + 4], s3 = row[p + 6];
        float x0 = xl[(size_t)s0 * HC + c];
        float x1 = xl[(size_t)s1 * HC + c];
        float x2 = xl[(size_t)s2 * HC + c];
        float x3 = xl[(size_t)s3 * HC + c];
        float z0 = x0 + xrc; z0 = z0 > 0.f ? z0 : 0.2f * z0;
        float z1 = x1 + xrc; z1 = z1 > 0.f ? z1 : 0.2f * z1;
        float z2 = x2 + xrc; z2 = z2 > 0.f ? z2 : 0.2f * z2;
        float z3 = x3 + xrc; z3 = z3 > 0.f ? z3 : 0.2f * z3;
        float t0 = z0 * attc, t1 = z1 * attc, t2 = z2 * attc, t3 = z3 * attc;
        t0 += __shfl_xor(t0, 1); t1 += __shfl_xor(t1, 1);
        t2 += __shfl_xor(t2, 1); t3 += __shfl_xor(t3, 1);
        t0 += __shfl_xor(t0, 2); t1 += __shfl_xor(t1, 2);
        t2 += __shfl_xor(t2, 2); t3 += __shfl_xor(t3, 2);
        t0 += __shfl_xor(t0, 4); t1 += __shfl_xor(t1, 4);
        t2 += __shfl_xor(t2, 4); t3 += __shfl_xor(t3, 4);
        t0 += __shfl_xor(t0, 8); t1 += __shfl_xor(t1, 8);
        t2 += __shfl_xor(t2, 8); t3 += __shfl_xor(t3, 8);
        float e0 = __expf(t0), e1 = __expf(t1);
        float e2 = __expf(t2), e3 = __expf(t3);
        den += (e0 + e1) + (e2 + e3);
        accv = fmaf(e0, x0, accv);
        accv = fmaf(e1, x1, accv);
        accv = fmaf(e2, x2, accv);
        accv = fmaf(e3, x3, accv);
    }
    for (; p < deg; p += 2) {
        int sid = row[p];
        float x0 = xl[(size_t)sid * HC + c];
        float z = x0 + xrc;
        z = z > 0.f ? z : 0.2f * z;
        float t = z * attc;
        t += __shfl_xor(t, 1);
        t += __shfl_xor(t, 2);
        t += __shfl_xor(t, 4);
        t += __shfl_xor(t, 8);
        float ex = __expf(t);
        den += ex;
        accv = fmaf(ex, x0, accv);
    }
    accv += __shfl_xor(accv, 32);
    den  += __shfl_xor(den, 32);
    if (eslot == 0) {
        float v = accv / (den + 1e-16f) + bc;
        v = v > 0.f ? v : expm1f(v);                 // ELU
        xr[(size_t)d * HC + c] = v;
    }
}

// ---------------- FC + log_softmax ------------------------------------------
__global__ __launch_bounds__(256) void fc_logsoftmax(
    const float* __restrict__ h, const float* __restrict__ W,
    const float* __restrict__ b, float* __restrict__ out, int N)
{
    int n = blockIdx.x * blockDim.x + threadIdx.x;
    if (n >= N) return;
    float hv[32];
    const float4* h4 = (const float4*)(h + (size_t)n * HC);
    #pragma unroll
    for (int j = 0; j < 8; ++j) {
        float4 t = h4[j];
        hv[j * 4 + 0] = t.x; hv[j * 4 + 1] = t.y;
        hv[j * 4 + 2] = t.z; hv[j * 4 + 3] = t.w;
    }
    float lg[7];
    #pragma unroll
    for (int c = 0; c < 7; ++c) lg[c] = b[c];
    #pragma unroll
    for (int k = 0; k < 32; ++k) {
        float hk = hv[k];
        #pragma unroll
        for (int c = 0; c < 7; ++c) lg[c] = fmaf(hk, W[k * 7 + c], lg[c]);
    }
    float m = lg[0];
    #pragma unroll
    for (int c = 1; c < 7; ++c) m = fmaxf(m, lg[c]);
    float sum = 0.f;
    #pragma unroll
    for (int c = 0; c < 7; ++c) sum += expf(lg[c] - m);
    float lse = m + logf(sum);
    #pragma unroll
    for (int c = 0; c < 7; ++c) out[(size_t)n * 7 + c] = lg[c] - lse;
}

extern "C" void kernel_launch(void* const* d_in, const int* in_sizes, int n_in,
                              void* d_out, int out_size, void* d_ws, size_t ws_size,
                              hipStream_t stream) {
    const float* x   = (const float*)d_in[0];
    const int*   ei  = (const int*)d_in[1];     // [2,E] int32
    const float* Wl1 = (const float*)d_in[2];
    const float* Wr1 = (const float*)d_in[3];
    const float* a1  = (const float*)d_in[4];
    const float* b1  = (const float*)d_in[5];
    const float* Wl2 = (const float*)d_in[6];
    const float* Wr2 = (const float*)d_in[7];
    const float* a2  = (const float*)d_in[8];
    const float* b2  = (const float*)d_in[9];
    const float* fcW = (const float*)d_in[10];
    const float* fcb = (const float*)d_in[11];
    float* out = (float*)d_out;

    const int Fin  = 1433;
    const int N    = in_sizes[0] / Fin;
    const int E    = in_sizes[1] / 2;
    const int Etot = E + N;

    float*  xl      = (float*)d_ws;                  // N*32
    float*  xr      = xl + (size_t)N * HC;           // N*32 (also layer output h)
    int*    cnt     = (int*)(xr + (size_t)N * HC);   // N
    int*    csr_src = cnt + N;                       // N*CAP
    __bf16* Wt      = (__bf16*)(csr_src + (size_t)N * CAP);  // 64*1440 bf16

    const int* srcp = ei;
    const int* dstp = ei + E;

    dim3 blk(256);
    dim3 gM((N + BM - 1) / BM);
    dim3 gN64((N + 63) / 64);
    dim3 gE((Etot + 255) / 256);
    dim3 gW((N * 64 + 255) / 256);
    dim3 gN((N + 255) / 256);
    dim3 gWp((64 * WTP + 255) / 256);

    // ---- W1 prep (bf16 transpose) + CSR build ----
    wprep<<<gWp, blk, 0, stream>>>(Wl1, Wr1, Wt);
    hipMemsetAsync(cnt, 0, (size_t)N * sizeof(int), stream);
    scatter_fixed<<<gE, blk, 0, stream>>>(srcp, dstp, E, Etot, cnt, csr_src);

    // ---- layer 1 (bf16 MFMA GEMM, no-LDS streaming) ----
    gemm_dual_mfma<<<gM, blk, 0, stream>>>(x, N, Wt, xl, xr);
    gather_pass<<<gW, blk, 0, stream>>>(xl, xr, a1, cnt, csr_src, b1, N);
    // ---- layer 2 (fp32, K=32; in-place safe) ----
    gemm_dual<<<gN64, blk, 0, stream>>>(xr, N, HC, Wl2, Wr2, xl, xr);
    gather_pass<<<gW, blk, 0, stream>>>(xl, xr, a2, cnt, csr_src, b2, N);
    // ---- FC + log_softmax ----
    fc_logsoftmax<<<gN, blk, 0, stream>>>(xr, fcW, fcb, out, N);
}

// Round 2
// 1283.515 us; speedup vs baseline: 1.1163x; 1.0464x over previous
//
#include <hip/hip_runtime.h>
#include <hip/hip_bf16.h>
#include <cstddef>
#include <cstdint>

#define HC 32      // H*C
#define NHEADS 2
#define CH 16
#define CAP 96     // fixed per-node edge bucket; P(deg>=96)~1e-18 for Poisson(33)

#define KK    1433   // Fin
#define KFULL 1408   // 44 full BK=32 tiles
#define NT_K  44     // number of full K tiles
#define WTP   1440   // padded Wt row stride (bf16), 16B-aligned rows

typedef __bf16 bf16x8 __attribute__((ext_vector_type(8)));
typedef float  f32x4  __attribute__((ext_vector_type(4)));

#define BM 128

// ---------------- W prep: fp32 [K][32]x2 -> bf16 transposed [64][1440] ------
// Wt[n][k] = (n<32 ? Wl[k][n] : Wr[k][n-32]), zero-padded for k>=1433.
__global__ __launch_bounds__(256) void wprep(
    const float* __restrict__ Wl, const float* __restrict__ Wr,
    __bf16* __restrict__ Wt)
{
    int idx = blockIdx.x * 256 + threadIdx.x;
    if (idx >= 64 * WTP) return;
    int n = idx / WTP;
    int k = idx - n * WTP;
    float v = 0.f;
    if (k < KK) v = (n < HC) ? Wl[(size_t)k * HC + n]
                             : Wr[(size_t)k * HC + (n - HC)];
    Wt[idx] = (__bf16)v;
}

// ---------------- Layer-1 GEMM: per-wave private LDS pipeline ---------------
// Each wave owns 32 rows x 64 cols. A staged fp32 via global_load_lds(width 4)
// into a wave-PRIVATE 32x32 LDS tile (double-buffered) -> no __syncthreads at
// all; ordering via counted s_waitcnt vmcnt(16). XOR-swizzle applied on the
// GLOBAL source (LDS dest linear, as global_load_lds requires) and undone on
// the ds_read_b128 side -> conflict-optimal reads. fp32->bf16 cvt in-reg.
// B fragments: direct 16B-aligned loads from L2-resident bf16 Wt.
__global__ __launch_bounds__(256) void gemm_dual_mfma(
    const float* __restrict__ A, int N,
    const __bf16* __restrict__ Wt,
    float* __restrict__ XL, float* __restrict__ XR)
{
    __shared__ float Abuf[2][4096];          // 2 x (4 waves x 32 rows x 32 f32)
    const int tid  = threadIdx.x;
    const int lane = tid & 63;
    const int w    = tid >> 6;
    const int row0 = blockIdx.x * BM;
    const int frag_m = lane & 15;
    const int frag_k = lane >> 4;            // 0..3

    f32x4 acc[2][4];
    #pragma unroll
    for (int i = 0; i < 2; ++i)
        #pragma unroll
        for (int j = 0; j < 4; ++j) acc[i][j] = (f32x4){0.f, 0.f, 0.f, 0.f};

    // staging geometry: wave stages its own rows [w*32, w*32+32)
    const int sr = lane >> 5;                // row parity within instr
    const int sd = lane & 31;                // dword slot within row
    // read-side swizzle key (depends only on frag_m & 7)
    const int fsw = (frag_m & 7) << 2;

    const __bf16* __restrict__ wb = Wt + (size_t)frag_m * WTP + frag_k * 8;

    // tail pointers (direct global, guarded)
    int r0g = row0 + w * 32 + frag_m;
    int r1g = r0g + 16;
    int cr0 = (r0g < N) ? r0g : N - 1;
    int cr1 = (r1g < N) ? r1g : N - 1;
    const float* __restrict__ a0 = A + (size_t)cr0 * KK + frag_k * 8;
    const float* __restrict__ a1 = A + (size_t)cr1 * KK + frag_k * 8;

    // ---- stage one 32x32 fp32 tile (wave-private) into Abuf[b] ----
    auto stage = [&](int b, int k0) {
        #pragma unroll
        for (int i = 0; i < 16; ++i) {
            int r  = 2 * i + sr;                       // local row 0..31
            int gr = row0 + w * 32 + r;
            if (gr >= N) gr = N - 1;                   // clamp; store-guarded
            int col = sd ^ ((r & 7) << 2);             // pre-swizzled source
            const float* gsrc = A + (size_t)gr * KK + (k0 + col);
            uint32_t* lbase = (uint32_t*)&Abuf[b][w * 1024 + i * 64];
            __builtin_amdgcn_global_load_lds(
                (const __attribute__((address_space(1))) uint32_t*)gsrc,
                (__attribute__((address_space(3))) uint32_t*)lbase, 4, 0, 0);
        }
    };

    // ---- MFMA on staged tile b with preloaded B fragments ----
    auto computeA = [&](int b, const bf16x8* bfv) {
        #pragma unroll
        for (int mt = 0; mt < 2; ++mt) {
            int r_l = mt * 16 + frag_m;
            const float* rb = &Abuf[b][w * 1024 + r_l * 32];
            f32x4 lo = *(const f32x4*)(rb + ((frag_k * 8) ^ fsw));
            f32x4 hi = *(const f32x4*)(rb + ((frag_k * 8 + 4) ^ fsw));
            bf16x8 af;
            #pragma unroll
            for (int j = 0; j < 4; ++j) {
                af[j]     = (__bf16)lo[j];
                af[j + 4] = (__bf16)hi[j];
            }
            #pragma unroll
            for (int nt = 0; nt < 4; ++nt)
                acc[mt][nt] = __builtin_amdgcn_mfma_f32_16x16x32_bf16(
                    af, bfv[nt], acc[mt][nt], 0, 0, 0);
        }
    };

    stage(0, 0);                                        // prologue: tile 0
    for (int t = 0; t < NT_K - 1; ++t) {
        // prior ds_reads fully retired before overwriting their buffer region
        asm volatile("s_waitcnt lgkmcnt(0)" ::: "memory");
        stage((t + 1) & 1, (t + 1) * 32);               // prefetch next tile
        bf16x8 bfv[4];                                  // B for current tile
        #pragma unroll
        for (int nt = 0; nt < 4; ++nt)
            bfv[nt] = *(const bf16x8*)(wb + (size_t)(nt * 16) * WTP + t * 32);
        asm volatile("s_waitcnt vmcnt(16)" ::: "memory"); // tile t landed
        __builtin_amdgcn_sched_barrier(0);
        computeA(t & 1, bfv);
    }
    {   // last full tile (no prefetch)
        bf16x8 bfv[4];
        #pragma unroll
        for (int nt = 0; nt < 4; ++nt)
            bfv[nt] = *(const bf16x8*)(wb + (size_t)(nt * 16) * WTP + (NT_K - 1) * 32);
        asm volatile("s_waitcnt vmcnt(0)" ::: "memory");
        __builtin_amdgcn_sched_barrier(0);
        computeA((NT_K - 1) & 1, bfv);
    }

    // ---- K tail (k = 1408..1432): A guarded per element; Wt zero-padded ----
    {
        bf16x8 af0, af1, bfv[4];
        #pragma unroll
        for (int j = 0; j < 8; ++j) {
            int k = KFULL + frag_k * 8 + j;
            float x0 = (k < KK) ? a0[KFULL + j] : 0.f;
            float x1 = (k < KK) ? a1[KFULL + j] : 0.f;
            af0[j] = (__bf16)x0;
            af1[j] = (__bf16)x1;
        }
        #pragma unroll
        for (int nt = 0; nt < 4; ++nt)
            bfv[nt] = *(const bf16x8*)(wb + (size_t)(nt * 16) * WTP + KFULL);
        #pragma unroll
        for (int nt = 0; nt < 4; ++nt) {
            acc[0][nt] = __builtin_amdgcn_mfma_f32_16x16x32_bf16(
                af0, bfv[nt], acc[0][nt], 0, 0, 0);
            acc[1][nt] = __builtin_amdgcn_mfma_f32_16x16x32_bf16(
                af1, bfv[nt], acc[1][nt], 0, 0, 0);
        }
    }

    // ---- epilogue (identical layout to verified version) ----
    const int cl = lane & 15;
    const int rq = (lane >> 4) * 4;
    #pragma unroll
    for (int mt = 0; mt < 2; ++mt) {
        #pragma unroll
        for (int nt = 0; nt < 4; ++nt) {
            int col = nt * 16 + cl;
            float* dst = (col < HC) ? XL : XR;
            int c = (col < HC) ? col : (col - HC);
            #pragma unroll
            for (int r = 0; r < 4; ++r) {
                int grow = row0 + w * 32 + mt * 16 + rq + r;
                if (grow < N) dst[(size_t)grow * HC + c] = acc[mt][nt][r];
            }
        }
    }
}

// ---------------- fp32 GEMM (layer 2, K=32; in-place safe A==XR) ------------
__global__ __launch_bounds__(256) void gemm_dual(
    const float* __restrict__ A, int N, int K,
    const float* __restrict__ Wl, const float* __restrict__ Wr,
    float* __restrict__ XL, float* __restrict__ XR)
{
    __shared__ __align__(16) float As[64][33];
    __shared__ __align__(16) float Ws[32][68];
    const int tid = threadIdx.x;
    const int tx = tid & 15;
    const int ty = tid >> 4;
    const int row0 = blockIdx.x * 64;

    float acc[4][4];
    #pragma unroll
    for (int i = 0; i < 4; ++i)
        #pragma unroll
        for (int j = 0; j < 4; ++j) acc[i][j] = 0.f;

    for (int k0 = 0; k0 < K; k0 += 32) {
        #pragma unroll
        for (int i = 0; i < 8; ++i) {
            int idx = tid + i * 256;
            int r = idx >> 5;
            int kk = idx & 31;
            int gr = row0 + r, gk = k0 + kk;
            As[r][kk] = (gr < N && gk < K) ? A[(size_t)gr * K + gk] : 0.f;
        }
        #pragma unroll
        for (int i = 0; i < 8; ++i) {
            int idx = tid + i * 256;
            int kk = idx >> 6;
            int c = idx & 63;
            int gk = k0 + kk;
            float v = 0.f;
            if (gk < K) v = (c < HC) ? Wl[(size_t)gk * HC + c]
                                     : Wr[(size_t)gk * HC + (c - HC)];
            Ws[kk][c] = v;
        }
        __syncthreads();
        #pragma unroll
        for (int kk = 0; kk < 32; ++kk) {
            const float4 bv = *(const float4*)(&Ws[kk][tx * 4]);
            float av[4];
            #pragma unroll
            for (int i = 0; i < 4; ++i) av[i] = As[ty * 4 + i][kk];
            #pragma unroll
            for (int i = 0; i < 4; ++i) {
                acc[i][0] = fmaf(av[i], bv.x, acc[i][0]);
                acc[i][1] = fmaf(av[i], bv.y, acc[i][1]);
                acc[i][2] = fmaf(av[i], bv.z, acc[i][2]);
                acc[i][3] = fmaf(av[i], bv.w, acc[i][3]);
            }
        }
        __syncthreads();
    }
    #pragma unroll
    for (int i = 0; i < 4; ++i) {
        int gr = row0 + ty * 4 + i;
        if (gr < N) {
            float4 v = make_float4(acc[i][0], acc[i][1], acc[i][2], acc[i][3]);
            int c0 = tx * 4;
            if (c0 < HC) *(float4*)&XL[(size_t)gr * HC + c0] = v;
            else         *(float4*)&XR[(size_t)gr * HC + (c0 - HC)] = v;
        }
    }
}

// ---------------- CSR build: single scatter into fixed-cap buckets ----------
__global__ __launch_bounds__(256) void scatter_fixed(
    const int* __restrict__ src, const int* __restrict__ dst,
    int E, int Etot, int* __restrict__ cnt, int* __restrict__ csr_src)
{
    int e = blockIdx.x * blockDim.x + threadIdx.x;
    if (e >= Etot) return;
    int si, di;
    if (e < E) { si = src[e]; di = dst[e]; }
    else       { si = e - E;  di = si; }
    int pos = atomicAdd(&cnt[di], 1);
    if (pos < CAP) csr_src[(size_t)di * CAP + pos] = si;
}

// ---------------- Gather: per-node softmax-aggregate + bias + ELU -----------
// One wave per dst node; 2 edge slots x 4-deep ILP = 8 edges in flight.
__global__ __launch_bounds__(256) void gather_pass(
    const float* __restrict__ xl, float* __restrict__ xr,
    const float* __restrict__ att, const int* __restrict__ cnt,
    const int* __restrict__ csr_src, const float* __restrict__ bias, int N)
{
    int d = (blockIdx.x * blockDim.x + threadIdx.x) >> 6;
    if (d >= N) return;
    const int lane = threadIdx.x & 63;
    const int c = lane & 31;
    const int eslot = lane >> 5;

    const float xrc  = xr[(size_t)d * HC + c];
    const float attc = att[c];
    const float bc   = bias[c];
    int deg = cnt[d]; if (deg > CAP) deg = CAP;
    const int* __restrict__ row = csr_src + (size_t)d * CAP;

    float accv = 0.f, den = 0.f;
    int p = eslot;
    for (; p + 6 < deg; p += 8) {
        int s0 = row[p], s1 = row[p + 2], s2 = row[p + 4], s3 = row[p + 6];
        float x0 = xl[(size_t)s0 * HC + c];
        float x1 = xl[(size_t)s1 * HC + c];
        float x2 = xl[(size_t)s2 * HC + c];
        float x3 = xl[(size_t)s3 * HC + c];
        float z0 = x0 + xrc; z0 = z0 > 0.f ? z0 : 0.2f * z0;
        float z1 = x1 + xrc; z1 = z1 > 0.f ? z1 : 0.2f * z1;
        float z2 = x2 + xrc; z2 = z2 > 0.f ? z2 : 0.2f * z2;
        float z3 = x3 + xrc; z3 = z3 > 0.f ? z3 : 0.2f * z3;
        float t0 = z0 * attc, t1 = z1 * attc, t2 = z2 * attc, t3 = z3 * attc;
        t0 += __shfl_xor(t0, 1); t1 += __shfl_xor(t1, 1);
        t2 += __shfl_xor(t2, 1); t3 += __shfl_xor(t3, 1);
        t0 += __shfl_xor(t0, 2); t1 += __shfl_xor(t1, 2);
        t2 += __shfl_xor(t2, 2); t3 += __shfl_xor(t3, 2);
        t0 += __shfl_xor(t0, 4); t1 += __shfl_xor(t1, 4);
        t2 += __shfl_xor(t2, 4); t3 += __shfl_xor(t3, 4);
        t0 += __shfl_xor(t0, 8); t1 += __shfl_xor(t1, 8);
        t2 += __shfl_xor(t2, 8); t3 += __shfl_xor(t3, 8);
        float e0 = __expf(t0), e1 = __expf(t1);
        float e2 = __expf(t2), e3 = __expf(t3);
        den += (e0 + e1) + (e2 + e3);
        accv = fmaf(e0, x0, accv);
        accv = fmaf(e1, x1, accv);
        accv = fmaf(e2, x2, accv);
        accv = fmaf(e3, x3, accv);
    }
    for (; p < deg; p += 2) {
        int sid = row[p];
        float x0 = xl[(size_t)sid * HC + c];
        float z = x0 + xrc;
        z = z > 0.f ? z : 0.2f * z;
        float t = z * attc;
        t += __shfl_xor(t, 1);
        t += __shfl_xor(t, 2);
        t += __shfl_xor(t, 4);
        t += __shfl_xor(t, 8);
        float ex = __expf(t);
        den += ex;
        accv = fmaf(ex, x0, accv);
    }
    accv += __shfl_xor(accv, 32);
    den  += __shfl_xor(den, 32);
    if (eslot == 0) {
        float v = accv / (den + 1e-16f) + bc;
        v = v > 0.f ? v : expm1f(v);                 // ELU
        xr[(size_t)d * HC + c] = v;
    }
}

// ---------------- FC + log_softmax ------------------------------------------
__global__ __launch_bounds__(256) void fc_logsoftmax(
    const float* __restrict__ h, const float* __restrict__ W,
    const float* __restrict__ b, float* __restrict__ out, int N)
{
    int n = blockIdx.x * blockDim.x + threadIdx.x;
    if (n >= N) return;
    float hv[32];
    const float4* h4 = (const float4*)(h + (size_t)n * HC);
    #pragma unroll
    for (int j = 0; j < 8; ++j) {
        float4 t = h4[j];
        hv[j * 4 + 0] = t.x; hv[j * 4 + 1] = t.y;
        hv[j * 4 + 2] = t.z; hv[j * 4 + 3] = t.w;
    }
    float lg[7];
    #pragma unroll
    for (int c = 0; c < 7; ++c) lg[c] = b[c];
    #pragma unroll
    for (int k = 0; k < 32; ++k) {
        float hk = hv[k];
        #pragma unroll
        for (int c = 0; c < 7; ++c) lg[c] = fmaf(hk, W[k * 7 + c], lg[c]);
    }
    float m = lg[0];
    #pragma unroll
    for (int c = 1; c < 7; ++c) m = fmaxf(m, lg[c]);
    float sum = 0.f;
    #pragma unroll
    for (int c = 0; c < 7; ++c) sum += expf(lg[c] - m);
    float lse = m + logf(sum);
    #pragma unroll
    for (int c = 0; c < 7; ++c) out[(size_t)n * 7 + c] = lg[c] - lse;
}

extern "C" void kernel_launch(void* const* d_in, const int* in_sizes, int n_in,
                              void* d_out, int out_size, void* d_ws, size_t ws_size,
                              hipStream_t stream) {
    const float* x   = (const float*)d_in[0];
    const int*   ei  = (const int*)d_in[1];     // [2,E] int32
    const float* Wl1 = (const float*)d_in[2];
    const float* Wr1 = (const float*)d_in[3];
    const float* a1  = (const float*)d_in[4];
    const float* b1  = (const float*)d_in[5];
    const float* Wl2 = (const float*)d_in[6];
    const float* Wr2 = (const float*)d_in[7];
    const float* a2  = (const float*)d_in[8];
    const float* b2  = (const float*)d_in[9];
    const float* fcW = (const float*)d_in[10];
    const float* fcb = (const float*)d_in[11];
    float* out = (float*)d_out;

    const int Fin  = 1433;
    const int N    = in_sizes[0] / Fin;
    const int E    = in_sizes[1] / 2;
    const int Etot = E + N;

    float*  xl      = (float*)d_ws;                  // N*32
    float*  xr      = xl + (size_t)N * HC;           // N*32 (also layer output h)
    int*    cnt     = (int*)(xr + (size_t)N * HC);   // N
    int*    csr_src = cnt + N;                       // N*CAP
    __bf16* Wt      = (__bf16*)(csr_src + (size_t)N * CAP);  // 64*1440 bf16

    const int* srcp = ei;
    const int* dstp = ei + E;

    dim3 blk(256);
    dim3 gM((N + BM - 1) / BM);
    dim3 gN64((N + 63) / 64);
    dim3 gE((Etot + 255) / 256);
    dim3 gW((N * 64 + 255) / 256);
    dim3 gN((N + 255) / 256);
    dim3 gWp((64 * WTP + 255) / 256);

    // ---- W1 prep (bf16 transpose) + CSR build ----
    wprep<<<gWp, blk, 0, stream>>>(Wl1, Wr1, Wt);
    hipMemsetAsync(cnt, 0, (size_t)N * sizeof(int), stream);
    scatter_fixed<<<gE, blk, 0, stream>>>(srcp, dstp, E, Etot, cnt, csr_src);

    // ---- layer 1 (bf16 MFMA GEMM, per-wave LDS pipeline) ----
    gemm_dual_mfma<<<gM, blk, 0, stream>>>(x, N, Wt, xl, xr);
    gather_pass<<<gW, blk, 0, stream>>>(xl, xr, a1, cnt, csr_src, b1, N);
    // ---- layer 2 (fp32, K=32; in-place safe) ----
    gemm_dual<<<gN64, blk, 0, stream>>>(xr, N, HC, Wl2, Wr2, xl, xr);
    gather_pass<<<gW, blk, 0, stream>>>(xl, xr, a2, cnt, csr_src, b2, N);
    // ---- FC + log_softmax ----
    fc_logsoftmax<<<gN, blk, 0, stream>>>(xr, fcW, fcb, out, N);
}